// Round 3
// baseline (330.672 us; speedup 1.0000x reference)
//
#include <hip/hip_runtime.h>

#define N_NODES 100000
#define N_EDGES 25000
#define N_INC   600000
#define D       128
#define CAP_E   64     // slab capacity per edge (mean deg 24, Poisson, >20 sigma)
#define CAP_N   32     // slab capacity per node (mean deg 6)
#define WTS     136    // LDS stride: 272B = 68 words == 4 mod 32 -> conflict-free b128

// k_front block ranges: scatter FIRST (latency-bound, overlaps with streaming cast)
#define SCAT_B  586    // 586*1024 >= 600000
#define CAST_B  6250   // 6250*256*8 = 12,800,000 elems exactly
#define WT_B    192
#define ATTR_B  782    // ceil(200000/256) float4s
#define FRONT_GRID (SCAT_B + CAST_B + WT_B + ATTR_B)

typedef __bf16 bf16x8 __attribute__((ext_vector_type(8)));
typedef float  f32x4  __attribute__((ext_vector_type(4)));

// ---------------- fused front-end: slab scatter + cast + wt_prep + attr copy ----------------

__global__ __launch_bounds__(256) void k_front(const float* __restrict__ X,
                                               __bf16* __restrict__ Xb,
                                               const int* __restrict__ ni,
                                               const int* __restrict__ ei,
                                               int* __restrict__ cnt_e,
                                               int* __restrict__ cnt_n,
                                               int* __restrict__ slab_e,
                                               int* __restrict__ slab_n,
                                               const float* __restrict__ W0,
                                               const float* __restrict__ W1,
                                               const float* __restrict__ W2,
                                               __bf16* __restrict__ Wt,
                                               const float* __restrict__ attr,
                                               float* __restrict__ out_attr) {
    int bx = blockIdx.x, t = threadIdx.x;

    if (bx < SCAT_B) {                       // ---- direct slab scatter (no sort, no scan) ----
        int base = bx * 1024;
#pragma unroll
        for (int j = 0; j < 4; j++) {
            int i = base + t + j * 256;
            if (i < N_INC) {
                int e = ei[i], n = ni[i];
                int pe = atomicAdd(&cnt_e[e], 1);
                if (pe < CAP_E) slab_e[(e << 6) + pe] = n;
                int pn = atomicAdd(&cnt_n[n], 1);
                if (pn < CAP_N) slab_n[(n << 5) + pn] = e;
            }
        }
        return;
    }
    if (bx < SCAT_B + CAST_B) {              // ---- x fp32 -> bf16 ----
        int i = (bx - SCAT_B) * 256 + t;
        float4 a = ((const float4*)X)[i * 2];
        float4 b = ((const float4*)X)[i * 2 + 1];
        bf16x8 r;
        r[0] = (__bf16)a.x; r[1] = (__bf16)a.y; r[2] = (__bf16)a.z; r[3] = (__bf16)a.w;
        r[4] = (__bf16)b.x; r[5] = (__bf16)b.y; r[6] = (__bf16)b.z; r[7] = (__bf16)b.w;
        *(bf16x8*)(Xb + i * 8) = r;
        return;
    }
    if (bx < SCAT_B + CAST_B + WT_B) {       // ---- Wt prep (3 layers) ----
        int lb = bx - (SCAT_B + CAST_B);
        int l = lb >> 6;
        int i = (lb & 63) * 256 + t;         // 0..16383
        const float* W = (l == 0) ? W0 : (l == 1) ? W1 : W2;
        int k = i >> 7, j = i & 127;
        Wt[l * 16384 + j * 128 + k] = (__bf16)W[i];
        return;
    }
    {                                        // ---- attr passthrough copy ----
        int lb = bx - (SCAT_B + CAST_B + WT_B);
        int i = lb * 256 + t;
        if (i < N_EDGES * 32 / 4)
            ((float4*)out_attr)[i] = ((const float4*)attr)[i];
    }
}

// ---------------- fused edge gather + GEMM (bf16 MFMA, Wt + ef tile in LDS) ----------------
// 16 edges/block, 16 lanes/edge gather (16-deep MLP); then 4 waves x 8 MFMA apply W.

__global__ __launch_bounds__(256) void eg_gemm(const __bf16* __restrict__ X,
                                               const int* __restrict__ cnt_e,
                                               const int* __restrict__ slab_e,
                                               const __bf16* __restrict__ Wt,
                                               __bf16* __restrict__ EF) {
    __shared__ __attribute__((aligned(16))) __bf16 WtS[128 * WTS];
    __shared__ __attribute__((aligned(16))) __bf16 efs[16 * WTS];
    int t = threadIdx.x;

    // dependent gather chain first (cnt -> list -> rows), then WtS bulk loads
    int e = blockIdx.x * 16 + (t >> 4);
    int lane16 = t & 15;
    int cnt = (e < N_EDGES) ? cnt_e[e] : 0;
    const int* lst = slab_e + ((size_t)e << 6);

    for (int i = t; i < 2048; i += 256) {
        int col = i >> 4, ch = i & 15;
        *(float4*)(WtS + col * WTS + ch * 8) = ((const float4*)Wt)[i];
    }

    int cc = (cnt < CAP_E) ? cnt : CAP_E;
    float acc[8] = {0.f, 0.f, 0.f, 0.f, 0.f, 0.f, 0.f, 0.f};
    for (int j = 0; j < cc; j += 16) {
        int idx[16]; float m[16];
#pragma unroll
        for (int k = 0; k < 16; k++) {
            int jj = j + k;
            bool ok = jj < cc;
            idx[k] = lst[ok ? jj : cc - 1];
            m[k] = ok ? 1.0f : 0.0f;
        }
        bf16x8 v[16];
#pragma unroll
        for (int k = 0; k < 16; k++)
            v[k] = *(const bf16x8*)(X + (size_t)idx[k] * 128 + lane16 * 8);
#pragma unroll
        for (int k = 0; k < 16; k++)
#pragma unroll
            for (int q = 0; q < 8; q++)
                acc[q] = fmaf(m[k], (float)v[k][q], acc[q]);
    }
    float binv = (cnt > 0) ? 1.0f / (float)cnt : 0.0f;
    bf16x8 r;
#pragma unroll
    for (int q = 0; q < 8; q++) r[q] = (__bf16)(acc[q] * binv);
    *(bf16x8*)(efs + (t >> 4) * WTS + lane16 * 8) = r;
    __syncthreads();

    int lane = t & 63, wave = t >> 6, quad = lane >> 4, lr = lane & 15;
    f32x4 o[2];
    o[0] = (f32x4){0.f, 0.f, 0.f, 0.f};
    o[1] = (f32x4){0.f, 0.f, 0.f, 0.f};
#pragma unroll
    for (int kk = 0; kk < 4; kk++) {
        bf16x8 a = *(const bf16x8*)(efs + lr * WTS + kk * 32 + quad * 8);
#pragma unroll
        for (int ct = 0; ct < 2; ct++) {
            bf16x8 bfr = *(const bf16x8*)(WtS + (wave * 32 + ct * 16 + lr) * WTS + kk * 32 + quad * 8);
            o[ct] = __builtin_amdgcn_mfma_f32_16x16x32_bf16(a, bfr, o[ct], 0, 0, 0);
        }
    }
#pragma unroll
    for (int ct = 0; ct < 2; ct++)
#pragma unroll
        for (int r4 = 0; r4 < 4; r4++) {
            int erow = blockIdx.x * 16 + quad * 4 + r4;
            if (erow < N_EDGES)
                EF[(size_t)erow * 128 + wave * 32 + ct * 16 + lr] = (__bf16)o[ct][r4];
        }
}

// ---------------- node gather: masked 8-wide, no serial tail ----------------
// mode 0: relu, bf16 out to hb; mode 1: no relu, fp32 out to of

__global__ __launch_bounds__(128) void node_gather(const __bf16* __restrict__ ef,
                                                   const int* __restrict__ cnt_n,
                                                   const int* __restrict__ slab_n,
                                                   const float* __restrict__ bias,
                                                   __bf16* __restrict__ hb,
                                                   float* __restrict__ of,
                                                   int mode) {
    int n = blockIdx.x * 8 + (threadIdx.x >> 4);
    int lane = threadIdx.x & 15;
    int cnt = cnt_n[n];
    const int* lst = slab_n + ((size_t)n << 5);
    int cc = (cnt < CAP_N) ? cnt : CAP_N;
    float acc[8] = {0.f, 0.f, 0.f, 0.f, 0.f, 0.f, 0.f, 0.f};
    for (int j = 0; j < cc; j += 8) {
        int idx[8]; float m[8];
#pragma unroll
        for (int k = 0; k < 8; k++) {
            int jj = j + k;
            bool ok = jj < cc;
            idx[k] = lst[ok ? jj : cc - 1];
            m[k] = ok ? 1.0f : 0.0f;
        }
        bf16x8 v[8];
#pragma unroll
        for (int k = 0; k < 8; k++)
            v[k] = *(const bf16x8*)(ef + (size_t)idx[k] * 128 + lane * 8);
#pragma unroll
        for (int k = 0; k < 8; k++)
#pragma unroll
            for (int q = 0; q < 8; q++)
                acc[q] = fmaf(m[k], (float)v[k][q], acc[q]);
    }
    float dinv = (cnt > 0) ? 1.0f / (float)cnt : 0.0f;
    float4 b0 = ((const float4*)bias)[lane * 2];
    float4 b1 = ((const float4*)bias)[lane * 2 + 1];
    float vals[8];
    vals[0] = acc[0] * dinv + b0.x; vals[1] = acc[1] * dinv + b0.y;
    vals[2] = acc[2] * dinv + b0.z; vals[3] = acc[3] * dinv + b0.w;
    vals[4] = acc[4] * dinv + b1.x; vals[5] = acc[5] * dinv + b1.y;
    vals[6] = acc[6] * dinv + b1.z; vals[7] = acc[7] * dinv + b1.w;
    if (mode == 0) {
        bf16x8 r;
#pragma unroll
        for (int k = 0; k < 8; k++) r[k] = (__bf16)fmaxf(vals[k], 0.f);
        *(bf16x8*)(hb + n * 128 + lane * 8) = r;
    } else {
        float4 o0 = make_float4(vals[0], vals[1], vals[2], vals[3]);
        float4 o1 = make_float4(vals[4], vals[5], vals[6], vals[7]);
        ((float4*)of)[n * 32 + lane * 2] = o0;
        ((float4*)of)[n * 32 + lane * 2 + 1] = o1;
    }
}

// ---------------- launch ----------------

extern "C" void kernel_launch(void* const* d_in, const int* in_sizes, int n_in,
                              void* d_out, int out_size, void* d_ws, size_t ws_size,
                              hipStream_t stream) {
    const float* x        = (const float*)d_in[0];
    const int* node_idx   = (const int*)d_in[1];
    const int* edge_idx   = (const int*)d_in[2];
    const float* attr     = (const float*)d_in[3];
    const float* Wl[3]    = {(const float*)d_in[4], (const float*)d_in[6], (const float*)d_in[8]};
    const float* bl[3]    = {(const float*)d_in[5], (const float*)d_in[7], (const float*)d_in[9]};
    float* out = (float*)d_out;

    char* ws = (char*)d_ws;
    __bf16* Xb  = (__bf16*)ws;                  // [0 .. 25,600,000)
    __bf16* Hb  = (__bf16*)(ws + 25600000);     // [25,600,000 .. 51,200,000)
    __bf16* EFy = (__bf16*)(ws + 57600000);     // 6.4 MB -> 64,000,000
    int* slab_e = (int*)(ws + 64000000);        // 25K*64*4 = 6,400,000 -> 70,400,000
    int* slab_n = (int*)(ws + 70400000);        // 100K*32*4 = 12,800,000 -> 83,200,000
    int* cnt_e  = (int*)(ws + 83200000);        // 100,000 B
    int* cnt_n  = (int*)(ws + 83300000);        // 400,000 B -> 83,700,000
    __bf16* Wt3 = (__bf16*)(ws + 83700000);     // 3 x 32,768 B

    hipMemsetAsync(cnt_e, 0, 500000, stream);   // cnt_e + cnt_n contiguous

    k_front<<<FRONT_GRID, 256, 0, stream>>>(x, Xb, node_idx, edge_idx,
                                            cnt_e, cnt_n, slab_e, slab_n,
                                            Wl[0], Wl[1], Wl[2], Wt3,
                                            attr, out + (size_t)N_NODES * D);

    for (int l = 0; l < 3; l++) {
        // linearity: D^-1 H B H^T (XW) = D^-1 H B ((H^T X) W)
        eg_gemm<<<(N_EDGES + 15) / 16, 256, 0, stream>>>(l == 0 ? Xb : Hb, cnt_e, slab_e,
                                                         Wt3 + l * 16384, EFy);
        node_gather<<<N_NODES / 8, 128, 0, stream>>>(EFy, cnt_n, slab_n, bl[l],
                                                     Hb, out, (l < 2) ? 0 : 1);
    }
}

// Round 4
// 296.403 us; speedup vs baseline: 1.1156x; 1.1156x over previous
//
#include <hip/hip_runtime.h>

#define N_NODES 100000
#define N_EDGES 25000
#define N_INC   600000
#define D       128
#define NB_EB   98     // edge buckets: 256 edges each (e>>8)
#define NB_NB   196    // node buckets: 512 nodes each (n>>9)
#define CAP_EB  8192   // slab capacity per edge bucket
#define CAP_NB  4096   // slab capacity per node bucket
#define WTS     136    // LDS stride: 272B = 68 words == 4 mod 32 -> conflict-free b128

// k_front block ranges: part_a FIRST (longest pole starts at t=0)
#define PA_B    586    // ceil(600000/1024)
#define PA_CHUNK 1024
#define CAST_B  6250   // 6250*256*8 = 12,800,000 elems exactly
#define WT_B    192
#define ATTR_B  782    // ceil(200000/256) float4s
#define FRONT_GRID (PA_B + CAST_B + WT_B + ATTR_B)

typedef __bf16 bf16x8 __attribute__((ext_vector_type(8)));
typedef float  f32x4  __attribute__((ext_vector_type(4)));

// ---------------- fused front-end: LDS-sorted part_a + cast + wt_prep + attr copy ----------------
// pairs_e word: node<<8 | (e&255); pairs_n word: edge<<9 | (n&511)
// staged words carry bucket id in the free high bits: e -> bkt<<25, n -> bkt<<24.

__global__ __launch_bounds__(256) void k_front(const float* __restrict__ X,
                                               __bf16* __restrict__ Xb,
                                               const int* __restrict__ ni,
                                               const int* __restrict__ ei,
                                               int* __restrict__ bcur_e,
                                               int* __restrict__ bcur_n,
                                               int* __restrict__ pairs_e,
                                               int* __restrict__ pairs_n,
                                               const float* __restrict__ W0,
                                               const float* __restrict__ W1,
                                               const float* __restrict__ W2,
                                               __bf16* __restrict__ Wt,
                                               const float* __restrict__ attr,
                                               float* __restrict__ out_attr) {
    __shared__ int he[NB_EB], hn[NB_NB];
    __shared__ int base_e[NB_EB], base_n[NB_NB];
    __shared__ int gb_e[NB_EB], gb_n[NB_NB];
    __shared__ unsigned stE[PA_CHUNK], stN[PA_CHUNK];
    __shared__ int ss[256];
    int bx = blockIdx.x, t = threadIdx.x;

    if (bx < PA_B) {                         // ---- part_a: LDS counting sort, coalesced dump ----
        if (t < NB_EB) he[t] = 0;
        if (t < NB_NB) hn[t] = 0;
        __syncthreads();
        int base = bx * PA_CHUNK;
        int total = N_INC - base; if (total > PA_CHUNK) total = PA_CHUNK;
        int se[4], sn[4], pe[4], pn[4];
#pragma unroll
        for (int j = 0; j < 4; j++) {
            int i = base + t + j * 256;
            if (i < N_INC) {
                se[j] = ei[i]; sn[j] = ni[i];
                pe[j] = atomicAdd(&he[se[j] >> 8], 1);
                pn[j] = atomicAdd(&hn[sn[j] >> 9], 1);
            } else se[j] = -1;
        }
        __syncthreads();
        // scan edge-bucket hist + reserve global slab space
        int v = (t < NB_EB) ? he[t] : 0;
        ss[t] = v;
        if (t < NB_EB) gb_e[t] = t * CAP_EB + atomicAdd(&bcur_e[t], v);
        __syncthreads();
        for (int o = 1; o < 256; o <<= 1) {
            int add = (t >= o) ? ss[t - o] : 0;
            __syncthreads();
            ss[t] += add;
            __syncthreads();
        }
        if (t < NB_EB) base_e[t] = ss[t] - v;
        __syncthreads();
        // scan node-bucket hist + reserve
        int v2 = (t < NB_NB) ? hn[t] : 0;
        ss[t] = v2;
        if (t < NB_NB) gb_n[t] = t * CAP_NB + atomicAdd(&bcur_n[t], v2);
        __syncthreads();
        for (int o = 1; o < 256; o <<= 1) {
            int add = (t >= o) ? ss[t - o] : 0;
            __syncthreads();
            ss[t] += add;
            __syncthreads();
        }
        if (t < NB_NB) base_n[t] = ss[t] - v2;
        __syncthreads();
        // LDS stage in sorted order
#pragma unroll
        for (int j = 0; j < 4; j++) {
            if (se[j] >= 0) {
                int b = se[j] >> 8;
                stE[base_e[b] + pe[j]] = ((unsigned)b << 25) | ((unsigned)sn[j] << 8) | (unsigned)(se[j] & 255);
                int b2 = sn[j] >> 9;
                stN[base_n[b2] + pn[j]] = ((unsigned)b2 << 24) | ((unsigned)se[j] << 9) | (unsigned)(sn[j] & 511);
            }
        }
        __syncthreads();
        // coalesced dump: consecutive staged positions in a bucket -> consecutive global addrs
        for (int p = t; p < total; p += 256) {
            unsigned w = stE[p];
            int b = w >> 25;
            pairs_e[gb_e[b] + (p - base_e[b])] = (int)(w & 0x1FFFFFFu);
            unsigned w2 = stN[p];
            int b2 = w2 >> 24;
            pairs_n[gb_n[b2] + (p - base_n[b2])] = (int)(w2 & 0xFFFFFFu);
        }
        return;
    }
    if (bx < PA_B + CAST_B) {                // ---- x fp32 -> bf16 ----
        int i = (bx - PA_B) * 256 + t;
        float4 a = ((const float4*)X)[i * 2];
        float4 b = ((const float4*)X)[i * 2 + 1];
        bf16x8 r;
        r[0] = (__bf16)a.x; r[1] = (__bf16)a.y; r[2] = (__bf16)a.z; r[3] = (__bf16)a.w;
        r[4] = (__bf16)b.x; r[5] = (__bf16)b.y; r[6] = (__bf16)b.z; r[7] = (__bf16)b.w;
        *(bf16x8*)(Xb + i * 8) = r;
        return;
    }
    if (bx < PA_B + CAST_B + WT_B) {         // ---- Wt prep (3 layers) ----
        int lb = bx - (PA_B + CAST_B);
        int l = lb >> 6;
        int i = (lb & 63) * 256 + t;         // 0..16383
        const float* W = (l == 0) ? W0 : (l == 1) ? W1 : W2;
        int k = i >> 7, j = i & 127;
        Wt[l * 16384 + j * 128 + k] = (__bf16)W[i];
        return;
    }
    {                                        // ---- attr passthrough copy ----
        int lb = bx - (PA_B + CAST_B + WT_B);
        int i = lb * 256 + t;
        if (i < N_EDGES * 32 / 4)
            ((float4*)out_attr)[i] = ((const float4*)attr)[i];
    }
}

// ---------------- fused CSR build: per-block bucket-offset scan, edges+nodes in one grid ----------------

__global__ __launch_bounds__(512) void k_csr(const int* __restrict__ pairs_e,
                                             const int* __restrict__ pairs_n,
                                             const int* __restrict__ bcur_e,
                                             const int* __restrict__ bcur_n,
                                             int* __restrict__ off_e,
                                             int* __restrict__ off_n,
                                             int* __restrict__ csr_e,
                                             int* __restrict__ csr_n) {
    __shared__ int ss[512], cur[512];
    int t = threadIdx.x;
    bool isE = blockIdx.x < NB_EB;
    int b = isE ? blockIdx.x : blockIdx.x - NB_EB;
    const int* pairs = isE ? (pairs_e + b * CAP_EB) : (pairs_n + b * CAP_NB);
    const int* bcur  = isE ? bcur_e : bcur_n;
    int nb    = isE ? NB_EB : NB_NB;
    int mask  = isE ? 255 : 511;
    int shift = isE ? 8 : 9;
    int nmax  = isE ? N_EDGES : N_NODES;
    int* off  = isE ? off_e : off_n;
    int* csr  = isE ? csr_e : csr_n;

    // bucket base offset: scan of final bucket counts
    ss[t] = (t < nb) ? bcur[t] : 0;
    __syncthreads();
    for (int o = 1; o < 512; o <<= 1) {
        int add = (t >= o) ? ss[t - o] : 0;
        __syncthreads();
        ss[t] += add;
        __syncthreads();
    }
    int ob = (b > 0) ? ss[b - 1] : 0;
    int cnt = ss[b] - ob;

    // per-id histogram within bucket
    cur[t] = 0;
    __syncthreads();
    for (int i = t; i < cnt; i += 512) atomicAdd(&cur[pairs[i] & mask], 1);
    __syncthreads();
    int v = cur[t];
    ss[t] = v;
    __syncthreads();
    for (int o = 1; o < 512; o <<= 1) {
        int add = (t >= o) ? ss[t - o] : 0;
        __syncthreads();
        ss[t] += add;
        __syncthreads();
    }
    int my = ob + ss[t] - v;
    int id = b * (mask + 1) + t;
    if (t <= mask && id < nmax) off[id] = my;
    __syncthreads();
    cur[t] = my;
    __syncthreads();
    for (int i = t; i < cnt; i += 512) {
        int u = pairs[i];
        int p = atomicAdd(&cur[u & mask], 1);
        csr[p] = u >> shift;
    }
    if (blockIdx.x == 0 && t == 0) { off_e[N_EDGES] = N_INC; off_n[N_NODES] = N_INC; }
}

// ---------------- fused edge gather + GEMM (bf16 MFMA, Wt + ef tile in LDS) ----------------
// 16 edges/block, 16 lanes/edge gather (16-deep MLP); then 4 waves x 8 MFMA apply W.

__global__ __launch_bounds__(256) void eg_gemm(const __bf16* __restrict__ X,
                                               const int* __restrict__ off_e,
                                               const int* __restrict__ csr_e,
                                               const __bf16* __restrict__ Wt,
                                               __bf16* __restrict__ EF) {
    __shared__ __attribute__((aligned(16))) __bf16 WtS[128 * WTS];
    __shared__ __attribute__((aligned(16))) __bf16 efs[16 * WTS];
    int t = threadIdx.x;

    // dependent gather chain first (off -> csr -> rows), then WtS bulk loads
    int e = blockIdx.x * 16 + (t >> 4);
    int lane16 = t & 15;
    int s = 0, tend = 0;
    if (e < N_EDGES) { s = off_e[e]; tend = off_e[e + 1]; }

    for (int i = t; i < 2048; i += 256) {
        int col = i >> 4, ch = i & 15;
        *(float4*)(WtS + col * WTS + ch * 8) = ((const float4*)Wt)[i];
    }

    float acc[8] = {0.f, 0.f, 0.f, 0.f, 0.f, 0.f, 0.f, 0.f};
    for (int j = s; j < tend; j += 16) {
        int idx[16]; float m[16];
#pragma unroll
        for (int k = 0; k < 16; k++) {
            int jj = j + k;
            bool ok = jj < tend;
            idx[k] = csr_e[ok ? jj : tend - 1];
            m[k] = ok ? 1.0f : 0.0f;
        }
        bf16x8 v[16];
#pragma unroll
        for (int k = 0; k < 16; k++)
            v[k] = *(const bf16x8*)(X + (size_t)idx[k] * 128 + lane16 * 8);
#pragma unroll
        for (int k = 0; k < 16; k++)
#pragma unroll
            for (int q = 0; q < 8; q++)
                acc[q] = fmaf(m[k], (float)v[k][q], acc[q]);
    }
    int cnt = tend - s;
    float binv = (cnt > 0) ? 1.0f / (float)cnt : 0.0f;
    bf16x8 r;
#pragma unroll
    for (int q = 0; q < 8; q++) r[q] = (__bf16)(acc[q] * binv);
    *(bf16x8*)(efs + (t >> 4) * WTS + lane16 * 8) = r;
    __syncthreads();

    int lane = t & 63, wave = t >> 6, quad = lane >> 4, lr = lane & 15;
    f32x4 o[2];
    o[0] = (f32x4){0.f, 0.f, 0.f, 0.f};
    o[1] = (f32x4){0.f, 0.f, 0.f, 0.f};
#pragma unroll
    for (int kk = 0; kk < 4; kk++) {
        bf16x8 a = *(const bf16x8*)(efs + lr * WTS + kk * 32 + quad * 8);
#pragma unroll
        for (int ct = 0; ct < 2; ct++) {
            bf16x8 bfr = *(const bf16x8*)(WtS + (wave * 32 + ct * 16 + lr) * WTS + kk * 32 + quad * 8);
            o[ct] = __builtin_amdgcn_mfma_f32_16x16x32_bf16(a, bfr, o[ct], 0, 0, 0);
        }
    }
#pragma unroll
    for (int ct = 0; ct < 2; ct++)
#pragma unroll
        for (int r4 = 0; r4 < 4; r4++) {
            int erow = blockIdx.x * 16 + quad * 4 + r4;
            if (erow < N_EDGES)
                EF[(size_t)erow * 128 + wave * 32 + ct * 16 + lr] = (__bf16)o[ct][r4];
        }
}

// ---------------- node gather: masked 8-wide, no serial tail ----------------
// mode 0: relu, bf16 out to hb; mode 1: no relu, fp32 out to of

__global__ __launch_bounds__(128) void node_gather(const __bf16* __restrict__ ef,
                                                   const int* __restrict__ off_n,
                                                   const int* __restrict__ csr_n,
                                                   const float* __restrict__ bias,
                                                   __bf16* __restrict__ hb,
                                                   float* __restrict__ of,
                                                   int mode) {
    int n = blockIdx.x * 8 + (threadIdx.x >> 4);
    int lane = threadIdx.x & 15;
    int s = off_n[n], tend = off_n[n + 1];
    float acc[8] = {0.f, 0.f, 0.f, 0.f, 0.f, 0.f, 0.f, 0.f};
    for (int j = s; j < tend; j += 8) {
        int idx[8]; float m[8];
#pragma unroll
        for (int k = 0; k < 8; k++) {
            int jj = j + k;
            bool ok = jj < tend;
            idx[k] = csr_n[ok ? jj : tend - 1];
            m[k] = ok ? 1.0f : 0.0f;
        }
        bf16x8 v[8];
#pragma unroll
        for (int k = 0; k < 8; k++)
            v[k] = *(const bf16x8*)(ef + (size_t)idx[k] * 128 + lane * 8);
#pragma unroll
        for (int k = 0; k < 8; k++)
#pragma unroll
            for (int q = 0; q < 8; q++)
                acc[q] = fmaf(m[k], (float)v[k][q], acc[q]);
    }
    int cnt = tend - s;
    float dinv = (cnt > 0) ? 1.0f / (float)cnt : 0.0f;
    float4 b0 = ((const float4*)bias)[lane * 2];
    float4 b1 = ((const float4*)bias)[lane * 2 + 1];
    float vals[8];
    vals[0] = acc[0] * dinv + b0.x; vals[1] = acc[1] * dinv + b0.y;
    vals[2] = acc[2] * dinv + b0.z; vals[3] = acc[3] * dinv + b0.w;
    vals[4] = acc[4] * dinv + b1.x; vals[5] = acc[5] * dinv + b1.y;
    vals[6] = acc[6] * dinv + b1.z; vals[7] = acc[7] * dinv + b1.w;
    if (mode == 0) {
        bf16x8 r;
#pragma unroll
        for (int k = 0; k < 8; k++) r[k] = (__bf16)fmaxf(vals[k], 0.f);
        *(bf16x8*)(hb + n * 128 + lane * 8) = r;
    } else {
        float4 o0 = make_float4(vals[0], vals[1], vals[2], vals[3]);
        float4 o1 = make_float4(vals[4], vals[5], vals[6], vals[7]);
        ((float4*)of)[n * 32 + lane * 2] = o0;
        ((float4*)of)[n * 32 + lane * 2 + 1] = o1;
    }
}

// ---------------- launch ----------------

extern "C" void kernel_launch(void* const* d_in, const int* in_sizes, int n_in,
                              void* d_out, int out_size, void* d_ws, size_t ws_size,
                              hipStream_t stream) {
    const float* x        = (const float*)d_in[0];
    const int* node_idx   = (const int*)d_in[1];
    const int* edge_idx   = (const int*)d_in[2];
    const float* attr     = (const float*)d_in[3];
    const float* Wl[3]    = {(const float*)d_in[4], (const float*)d_in[6], (const float*)d_in[8]};
    const float* bl[3]    = {(const float*)d_in[5], (const float*)d_in[7], (const float*)d_in[9]};
    float* out = (float*)d_out;

    char* ws = (char*)d_ws;
    __bf16* Xb  = (__bf16*)ws;                  // [0 .. 25,600,000)
    __bf16* Hb  = (__bf16*)(ws + 25600000);     // [25,600,000 .. 51,200,000)
    __bf16* EFy = (__bf16*)(ws + 57600000);     // 6.4 MB
    int* csr_e = (int*)(ws + 64000000);         // 2,400,000 B
    int* csr_n = (int*)(ws + 66400000);         // 2,400,000 B
    int* off_e = (int*)(ws + 68800000);         // 100,004 B
    int* off_n = (int*)(ws + 68950000);         // 400,004 B
    int* ib    = (int*)(ws + 69400000);         // bcur_e(98), bcur_n(196)
    int* bcur_e = ib;
    int* bcur_n = ib + 98;
    __bf16* Wt3 = (__bf16*)(ws + 69450000);     // 3 x 32,768 B
    // strided pair slabs live in Hb region during CSR build
    int* pairs_e = (int*)(ws + 25600000);       // 98*8192*4  = 3,211,264 B
    int* pairs_n = (int*)(ws + 28900000);       // 196*4096*4 = 3,211,264 B

    hipMemsetAsync(bcur_e, 0, 294 * sizeof(int), stream);

    k_front<<<FRONT_GRID, 256, 0, stream>>>(x, Xb, node_idx, edge_idx,
                                            bcur_e, bcur_n, pairs_e, pairs_n,
                                            Wl[0], Wl[1], Wl[2], Wt3,
                                            attr, out + (size_t)N_NODES * D);
    k_csr<<<NB_EB + NB_NB, 512, 0, stream>>>(pairs_e, pairs_n, bcur_e, bcur_n,
                                             off_e, off_n, csr_e, csr_n);

    for (int l = 0; l < 3; l++) {
        // linearity: D^-1 H B H^T (XW) = D^-1 H B ((H^T X) W)
        eg_gemm<<<(N_EDGES + 15) / 16, 256, 0, stream>>>(l == 0 ? Xb : Hb, off_e, csr_e,
                                                         Wt3 + l * 16384, EFy);
        node_gather<<<N_NODES / 8, 128, 0, stream>>>(EFy, off_n, csr_n, bl[l],
                                                     Hb, out, (l < 2) ? 0 : 1);
    }
}